// Round 2
// baseline (618.835 us; speedup 1.0000x reference)
//
#include <hip/hip_runtime.h>
#include <hip/hip_bf16.h>

#define RES 128
#define R3  (RES * RES * RES)   // 2097152

// Problem-fixed shapes (from reference setup_inputs)
constexpr int Bn = 4, Cn = 16, Hn = 256, Wn = 256, FHn = 32, FWn = 32;
constexpr int HW = Hn * Wn;     // 65536
constexpr int NPIX = Bn * HW;   // 262144

// ---------------------------------------------------------------------------
// Zero the 512 MiB output with 16B vector stores (harness poisons it 0xAA).
// ---------------------------------------------------------------------------
__global__ void zero_out_k(float4* __restrict__ out, int n4) {
    int i = blockIdx.x * blockDim.x + threadIdx.x;
    if (i < n4) out[i] = make_float4(0.f, 0.f, 0.f, 0.f);
}

// ---------------------------------------------------------------------------
// Init per-batch lower mins (fp64) to BIG (ws is poisoned 0xAA each call).
// ---------------------------------------------------------------------------
__global__ void init_lower_k(double* __restrict__ lower) {
    int i = threadIdx.x;
    if (i < Bn * 3) lower[i] = 1e10;
}

// Validity predicate in fp64 to match a float64 numpy reference exactly.
// sigmoid(x) > 0.75 AND all 3 nocs channels strictly positive.
__device__ __forceinline__ bool pixel_valid(const float* __restrict__ nocs,
                                            const float* __restrict__ mlog,
                                            int p, double& n0, double& n1, double& n2) {
    double x  = (double)mlog[p];
    double sg = 1.0 / (1.0 + exp(-x));
    if (!(sg > 0.75)) return false;
    int b  = p >> 16;        // p / HW
    int hw = p & (HW - 1);
    const float* nb = nocs + (size_t)b * 3 * HW + hw;
    n0 = (double)nb[0];
    n1 = (double)nb[HW];
    n2 = (double)nb[2 * HW];
    return (n0 > 0.0) & (n1 > 0.0) & (n2 > 0.0);
}

// ---------------------------------------------------------------------------
// Pass 1: per-batch fp64 min of pc over valid pixels.
// pc = (nocs + translation) * scale. All valid pc >= 0 so unsigned-bit
// atomicMin on the fp64 bit pattern preserves float ordering.
// ---------------------------------------------------------------------------
__global__ __launch_bounds__(256) void reduce_lower_k(
        const float* __restrict__ nocs, const float* __restrict__ mlog,
        const float* __restrict__ trans, const float* __restrict__ scale,
        unsigned long long* __restrict__ lower_bits) {
    __shared__ double s0[256], s1[256], s2[256];
    int tid = threadIdx.x;
    int p   = blockIdx.x * 256 + tid;
    int b   = p >> 16;                 // whole block shares b (HW % 256 == 0)

    double m0 = 1e10, m1 = 1e10, m2 = 1e10;
    double n0, n1, n2;
    if (pixel_valid(nocs, mlog, p, n0, n1, n2)) {
        double sc = (double)scale[b];
        double t0 = (double)trans[b * 3 + 0];
        double t1 = (double)trans[b * 3 + 1];
        double t2 = (double)trans[b * 3 + 2];
        m0 = (n0 + t0) * sc;
        m1 = (n1 + t1) * sc;
        m2 = (n2 + t2) * sc;
    }
    s0[tid] = m0; s1[tid] = m1; s2[tid] = m2;
    __syncthreads();
    #pragma unroll
    for (int off = 128; off > 0; off >>= 1) {
        if (tid < off) {
            s0[tid] = fmin(s0[tid], s0[tid + off]);
            s1[tid] = fmin(s1[tid], s1[tid + off]);
            s2[tid] = fmin(s2[tid], s2[tid + off]);
        }
        __syncthreads();
    }
    if (tid == 0) {
        atomicMin(&lower_bits[b * 3 + 0], (unsigned long long)__double_as_longlong(s0[0]));
        atomicMin(&lower_bits[b * 3 + 1], (unsigned long long)__double_as_longlong(s1[0]));
        atomicMin(&lower_bits[b * 3 + 2], (unsigned long long)__double_as_longlong(s2[0]));
    }
}

// ---------------------------------------------------------------------------
// Pass 2: scatter-add upsampled features into the voxel grid.
// idx = clip(floor(p0*128)*128^2 + floor(p1*128)*128 + floor(p2*128), 0, R3-1)
// entirely in fp64 (deterministic IEEE ops == numpy float64 reference).
// ---------------------------------------------------------------------------
__global__ __launch_bounds__(256) void scatter_k(
        const float* __restrict__ nocs, const float* __restrict__ mlog,
        const float* __restrict__ feat, const float* __restrict__ trans,
        const float* __restrict__ scale, const double* __restrict__ lower,
        float* __restrict__ out) {
    int p = blockIdx.x * 256 + threadIdx.x;
    double n0, n1, n2;
    if (!pixel_valid(nocs, mlog, p, n0, n1, n2)) return;

    int b  = p >> 16;
    int hw = p & (HW - 1);
    int h  = hw >> 8;        // / Wn
    int w  = hw & (Wn - 1);

    double sc = (double)scale[b];
    double l0 = lower[b * 3 + 0], l1 = lower[b * 3 + 1], l2 = lower[b * 3 + 2];
    double t0 = (double)trans[b * 3 + 0];
    double t1 = (double)trans[b * 3 + 1];
    double t2 = (double)trans[b * 3 + 2];

    double p0 = (n0 + t0) * sc - l0;
    double p1 = (n1 + t1) * sc - l1;
    double p2 = (n2 + t2) * sc - l2;

    int v0 = (int)floor(p0 * 128.0);
    int v1 = (int)floor(p1 * 128.0);
    int v2 = (int)floor(p2 * 128.0);

    int idx = v0 * (RES * RES) + v1 * RES + v2;
    idx = min(max(idx, 0), R3 - 1);

    // nearest-upsample feature sample: feature[b, c, h/8, w/8]
    const float* fbase = feat + (size_t)b * Cn * FHn * FWn + (h >> 3) * FWn + (w >> 3);
    float* obase = out + (size_t)b * Cn * R3 + idx;
    #pragma unroll
    for (int c = 0; c < Cn; ++c) {
        atomicAdd(obase + (size_t)c * R3, fbase[(size_t)c * FHn * FWn]);
    }
}

extern "C" void kernel_launch(void* const* d_in, const int* in_sizes, int n_in,
                              void* d_out, int out_size, void* d_ws, size_t ws_size,
                              hipStream_t stream) {
    const float* nocs  = (const float*)d_in[0];
    const float* mlog  = (const float*)d_in[1];
    const float* feat  = (const float*)d_in[2];
    const float* trans = (const float*)d_in[3];
    const float* scale = (const float*)d_in[4];
    float* out = (float*)d_out;
    double* lower = (double*)d_ws;         // 12 doubles of scratch

    // 1) init per-batch mins (tiny, launch first)
    init_lower_k<<<1, 64, 0, stream>>>(lower);

    // 2) per-batch fp64 min reduction over valid pixels
    reduce_lower_k<<<NPIX / 256, 256, 0, stream>>>(nocs, mlog, trans, scale,
                                                   (unsigned long long*)lower);

    // 3) zero the 512 MiB output grid
    int n4 = out_size / 4;
    zero_out_k<<<(n4 + 255) / 256, 256, 0, stream>>>((float4*)out, n4);

    // 4) scatter-add features into the grid
    scatter_k<<<NPIX / 256, 256, 0, stream>>>(nocs, mlog, feat, trans, scale,
                                              lower, out);
}